// Round 1
// baseline (1531.881 us; speedup 1.0000x reference)
//
#include <hip/hip_runtime.h>

#define N_NODES 40000
#define M_EDGES 10000
#define NNZ_CNT 400000
#define FT_DIM  128
#define HID     256
#define NCLS    10
#define NG      128
#define EPSV    1e-5f

// ---------------- utility ----------------
__global__ void fzero(float* __restrict__ p, int n) {
    int i = blockIdx.x * 256 + threadIdx.x;
    if (i < n) p[i] = 0.f;
}

// ---------------- CSR build ----------------
__global__ void count_kernel(const int* __restrict__ ni, const int* __restrict__ ei,
                             int* __restrict__ cnt_e, int* __restrict__ cnt_n) {
    int i = blockIdx.x * 256 + threadIdx.x;
    if (i < NNZ_CNT) {
        atomicAdd(&cnt_e[ei[i]], 1);
        atomicAdd(&cnt_n[ni[i]], 1);
    }
}

__global__ __launch_bounds__(1024) void exscan_kernel(const int* __restrict__ in,
                                                      int* __restrict__ out, int n) {
    __shared__ int lds[1024];
    __shared__ int carry_s;
    int tid = threadIdx.x;
    if (tid == 0) carry_s = 0;
    __syncthreads();
    for (int base = 0; base < n; base += 1024) {
        int i = base + tid;
        int v = (i < n) ? in[i] : 0;
        int x = v;
        lds[tid] = x;
        __syncthreads();
        for (int offd = 1; offd < 1024; offd <<= 1) {
            int t = (tid >= offd) ? lds[tid - offd] : 0;
            __syncthreads();
            x += t;
            lds[tid] = x;
            __syncthreads();
        }
        int carry = carry_s;
        if (i < n) out[i] = carry + x - v;   // exclusive
        __syncthreads();
        if (tid == 1023) carry_s = carry + x;
        __syncthreads();
    }
    if (tid == 0) out[n] = carry_s;
}

__global__ void fill_kernel(const int* __restrict__ ni, const int* __restrict__ ei,
                            const int* __restrict__ off_e, const int* __restrict__ off_n,
                            int* __restrict__ cur_e, int* __restrict__ cur_n,
                            int* __restrict__ idx_e, int* __restrict__ idx_n) {
    int i = blockIdx.x * 256 + threadIdx.x;
    if (i < NNZ_CNT) {
        int e = ei[i], n = ni[i];
        int pe = atomicAdd(&cur_e[e], 1);
        idx_e[off_e[e] + pe] = n;
        int pn = atomicAdd(&cur_n[n], 1);
        idx_n[off_n[n] + pn] = e;
    }
}

__global__ void dinv_kernel(const int* __restrict__ off_n, const int* __restrict__ idx_n,
                            const int* __restrict__ cnt_e, float* __restrict__ dinv) {
    int n = blockIdx.x * 256 + threadIdx.x;
    if (n < N_NODES) {
        int s = off_n[n], e = off_n[n + 1];
        float p = 0.f;
        for (int j = s; j < e; ++j) p += (float)cnt_e[idx_n[j]];
        dinv[n] = (p > 0.f) ? 1.0f / p : 1.0f;
    }
}

// ---------------- SpMM: out[r,:] = sum_{j in row r} Y[idx[j],:] (optionally * scale[r]) ----------------
// grid.x = #rows, blockDim.x = feature width d (128 or 256)
__global__ void spmm_kernel(const int* __restrict__ off, const int* __restrict__ idx,
                            const float* __restrict__ Y, float* __restrict__ out,
                            const float* __restrict__ scale) {
    int r = blockIdx.x;
    int f = threadIdx.x;
    int d = blockDim.x;
    int s = off[r], e = off[r + 1];
    float acc = 0.f;
    for (int j = s; j < e; ++j) {
        int src = __builtin_amdgcn_readfirstlane(idx[j]);
        acc += Y[(long)src * d + f];
    }
    if (scale) acc *= scale[r];
    out[(long)r * d + f] = acc;
}

// ---------------- fp32 GEMM: C[M x 256] = A[M x K] @ B[K x 256] + bias ----------------
// grid = (M/64, 4), block = 256, 64x64 tile, 4x4 microtile
__global__ __launch_bounds__(256) void gemm_bias(const float* __restrict__ A,
                                                 const float* __restrict__ B,
                                                 const float* __restrict__ bias,
                                                 float* __restrict__ C, int K) {
    __shared__ float As[64][33];
    __shared__ float Bs[32][64];
    int tid = threadIdx.x;
    int tx = tid & 15;
    int ty = tid >> 4;
    long row0 = (long)blockIdx.x * 64;
    int col0 = blockIdx.y * 64;
    float acc[4][4] = {{0.f}};
    for (int k0 = 0; k0 < K; k0 += 32) {
#pragma unroll
        for (int p = 0; p < 2; ++p) {
            int lin = p * 256 + tid;            // 0..511
            int r  = lin >> 3;                  // 0..63
            int kq = lin & 7;                   // 8 float4 per A row-chunk
            float4 av = *(const float4*)(A + (row0 + r) * (long)K + k0 + kq * 4);
            As[r][kq * 4 + 0] = av.x;
            As[r][kq * 4 + 1] = av.y;
            As[r][kq * 4 + 2] = av.z;
            As[r][kq * 4 + 3] = av.w;
            int kb = lin >> 4;                  // 0..31
            int nq = lin & 15;                  // 16 float4 per B row-chunk
            *(float4*)(&Bs[kb][nq * 4]) =
                *(const float4*)(B + (long)(k0 + kb) * HID + col0 + nq * 4);
        }
        __syncthreads();
#pragma unroll
        for (int kk = 0; kk < 32; ++kk) {
            float a[4], b[4];
#pragma unroll
            for (int i = 0; i < 4; ++i) a[i] = As[ty * 4 + i][kk];
            float4 bv = *(const float4*)(&Bs[kk][tx * 4]);
            b[0] = bv.x; b[1] = bv.y; b[2] = bv.z; b[3] = bv.w;
#pragma unroll
            for (int i = 0; i < 4; ++i)
#pragma unroll
                for (int j = 0; j < 4; ++j) acc[i][j] += a[i] * b[j];
        }
        __syncthreads();
    }
#pragma unroll
    for (int i = 0; i < 4; ++i) {
        long row = row0 + ty * 4 + i;
        int col = col0 + tx * 4;
        float4 o;
        o.x = acc[i][0] + bias[col + 0];
        o.y = acc[i][1] + bias[col + 1];
        o.z = acc[i][2] + bias[col + 2];
        o.w = acc[i][3] + bias[col + 3];
        *(float4*)(C + row * HID + col) = o;
    }
}

// ---------------- BatchNorm ----------------
__global__ __launch_bounds__(256) void bn_stats(const float* __restrict__ T, int rows,
                                                float* __restrict__ sums) {
    int f = threadIdx.x;
    int r0 = blockIdx.x * 256;
    int r1 = min(r0 + 256, rows);
    float s = 0.f, s2 = 0.f;
    for (int r = r0; r < r1; ++r) {
        float v = T[(long)r * HID + f];
        s += v;
        s2 += v * v;
    }
    atomicAdd(&sums[f], s);
    atomicAdd(&sums[HID + f], s2);
}

__global__ void bn_finalize(const float* __restrict__ sums, const float* __restrict__ g,
                            const float* __restrict__ be, float rows_inv,
                            float* __restrict__ a, float* __restrict__ c) {
    int f = threadIdx.x;   // 256 threads
    float mean = sums[f] * rows_inv;
    float var = sums[HID + f] * rows_inv - mean * mean;
    float av = g[f] * rsqrtf(var + EPSV);
    a[f] = av;
    c[f] = be[f] - mean * av;
}

__global__ void bn_relu_apply(float4* __restrict__ t, int n4, const float* __restrict__ a,
                              const float* __restrict__ c) {
    int i = blockIdx.x * 256 + threadIdx.x;
    if (i < n4) {
        int col = (i * 4) & (HID - 1);
        float4 v = t[i];
        v.x = fmaxf(fmaf(a[col + 0], v.x, c[col + 0]), 0.f);
        v.y = fmaxf(fmaf(a[col + 1], v.y, c[col + 1]), 0.f);
        v.z = fmaxf(fmaf(a[col + 2], v.z, c[col + 2]), 0.f);
        v.w = fmaxf(fmaf(a[col + 3], v.w, c[col + 3]), 0.f);
        t[i] = v;
    }
}

// ---------------- head: out_nodes[N x 10] (+)= q[N x 256] @ Wh[256 x 10] ----------------
__global__ __launch_bounds__(256) void head_kernel(const float* __restrict__ q,
                                                   const float* __restrict__ Wh,
                                                   const float* __restrict__ hb,
                                                   float* __restrict__ on, int mode) {
    int lane = threadIdx.x & 63;
    int w = threadIdx.x >> 6;
    int row = blockIdx.x * 4 + w;
    if (row >= N_NODES) return;
    float acc[NCLS];
#pragma unroll
    for (int c = 0; c < NCLS; ++c) acc[c] = 0.f;
#pragma unroll
    for (int it = 0; it < 4; ++it) {
        int f = lane + 64 * it;
        float v = q[(long)row * HID + f];
#pragma unroll
        for (int c = 0; c < NCLS; ++c) acc[c] += v * Wh[f * NCLS + c];
    }
#pragma unroll
    for (int c = 0; c < NCLS; ++c) {
#pragma unroll
        for (int m = 32; m >= 1; m >>= 1) acc[c] += __shfl_xor(acc[c], m, 64);
    }
    if (lane == 0) {
        if (mode == 0) {
#pragma unroll
            for (int c = 0; c < NCLS; ++c) on[(long)row * NCLS + c] = acc[c] + hb[c];
        } else {
#pragma unroll
            for (int c = 0; c < NCLS; ++c) on[(long)row * NCLS + c] += acc[c];
        }
    }
}

// ---------------- readout: per-graph mean ----------------
__global__ __launch_bounds__(256) void readout_accum(const float* __restrict__ on,
                                                     const int* __restrict__ ab,
                                                     float* __restrict__ racc,
                                                     float* __restrict__ rcnt) {
    __shared__ float lacc[NG * NCLS];
    __shared__ float lcnt[NG];
    int tid = threadIdx.x;
    for (int i = tid; i < NG * NCLS; i += 256) lacc[i] = 0.f;
    if (tid < NG) lcnt[tid] = 0.f;
    __syncthreads();
    int n = blockIdx.x * 256 + tid;
    if (n < N_NODES) {
        int b = ab[n];
        atomicAdd(&lcnt[b], 1.0f);
        for (int c = 0; c < NCLS; ++c) atomicAdd(&lacc[b * NCLS + c], on[(long)n * NCLS + c]);
    }
    __syncthreads();
    if (tid < NG && lcnt[tid] > 0.f) {
        atomicAdd(&rcnt[tid], lcnt[tid]);
        for (int c = 0; c < NCLS; ++c) atomicAdd(&racc[tid * NCLS + c], lacc[tid * NCLS + c]);
    }
}

__global__ void readout_final(const float* __restrict__ racc, const float* __restrict__ rcnt,
                              float* __restrict__ out) {
    int i = blockIdx.x * 256 + threadIdx.x;
    if (i < NG * NCLS) out[i] = racc[i] / fmaxf(rcnt[i / NCLS], 1.0f);
}

// ---------------- launch ----------------
extern "C" void kernel_launch(void* const* d_in, const int* in_sizes, int n_in,
                              void* d_out, int out_size, void* d_ws, size_t ws_size,
                              hipStream_t stream) {
    const float* X         = (const float*)d_in[0];
    const int*   node_idx  = (const int*)d_in[1];
    const int*   edge_idx  = (const int*)d_in[2];
    const int*   all_batch = (const int*)d_in[3];
    const float* W1[2]  = {(const float*)d_in[4],  (const float*)d_in[12]};
    const float* b1[2]  = {(const float*)d_in[5],  (const float*)d_in[13]};
    const float* g1[2]  = {(const float*)d_in[6],  (const float*)d_in[14]};
    const float* be1[2] = {(const float*)d_in[7],  (const float*)d_in[15]};
    const float* W2[2]  = {(const float*)d_in[8],  (const float*)d_in[16]};
    const float* b2[2]  = {(const float*)d_in[9],  (const float*)d_in[17]};
    const float* bng[2] = {(const float*)d_in[10], (const float*)d_in[18]};
    const float* bnb[2] = {(const float*)d_in[11], (const float*)d_in[19]};
    const float* headW  = (const float*)d_in[20];
    const float* headb  = (const float*)d_in[21];
    float* out = (float*)d_out;

    char* base = (char*)d_ws;
    size_t off = 0;
    auto alloc = [&](size_t bytes) -> void* {
        size_t o = (off + 255) & ~(size_t)255;
        off = o + bytes;
        return (void*)(base + o);
    };

    // counts + cursors contiguous so one zero pass covers them
    int* ibase  = (int*)alloc((size_t)(2 * M_EDGES + 2 * N_NODES) * 4);
    int* cnt_e  = ibase;
    int* cnt_n  = cnt_e + M_EDGES;
    int* cur_e  = cnt_n + N_NODES;
    int* cur_n  = cur_e + M_EDGES;
    int* off_e  = (int*)alloc((M_EDGES + 1) * 4);
    int* off_n  = (int*)alloc((N_NODES + 1) * 4);
    int* idx_e  = (int*)alloc((size_t)NNZ_CNT * 4);
    int* idx_n  = (int*)alloc((size_t)NNZ_CNT * 4);
    float* dinv = (float*)alloc((size_t)N_NODES * 4);
    float* ebuf = (float*)alloc((size_t)M_EDGES * HID * 4);
    float* P    = (float*)alloc((size_t)N_NODES * HID * 4);
    float* T    = (float*)alloc((size_t)N_NODES * HID * 4);
    float* H    = (float*)alloc((size_t)N_NODES * HID * 4);
    float* onodes = (float*)alloc((size_t)N_NODES * NCLS * 4);
    float* bnsums = (float*)alloc(2 * HID * 4);
    float* bn_a   = (float*)alloc(HID * 4);
    float* bn_c   = (float*)alloc(HID * 4);
    float* racc   = (float*)alloc((NG * NCLS + NG) * 4);  // racc then rcnt contiguous
    float* rcnt   = racc + NG * NCLS;

    const int nnz_blocks = (NNZ_CNT + 255) / 256;

    // --- CSR build + degree norm ---
    fzero<<<(2 * M_EDGES + 2 * N_NODES + 255) / 256, 256, 0, stream>>>((float*)ibase,
                                                                       2 * M_EDGES + 2 * N_NODES);
    count_kernel<<<nnz_blocks, 256, 0, stream>>>(node_idx, edge_idx, cnt_e, cnt_n);
    exscan_kernel<<<1, 1024, 0, stream>>>(cnt_e, off_e, M_EDGES);
    exscan_kernel<<<1, 1024, 0, stream>>>(cnt_n, off_n, N_NODES);
    fill_kernel<<<nnz_blocks, 256, 0, stream>>>(node_idx, edge_idx, off_e, off_n,
                                                cur_e, cur_n, idx_e, idx_n);
    dinv_kernel<<<(N_NODES + 255) / 256, 256, 0, stream>>>(off_n, idx_n, cnt_e, dinv);

    const float rows_inv = 1.0f / (float)N_NODES;
    const int n4 = N_NODES * HID / 4;
    const float* hin = X;
    int din = FT_DIM;

    for (int L = 0; L < 2; ++L) {
        // pooled = H (H^T hin)
        spmm_kernel<<<M_EDGES, din, 0, stream>>>(off_e, idx_e, hin, ebuf, nullptr);
        spmm_kernel<<<N_NODES, din, 0, stream>>>(off_n, idx_n, ebuf, P, nullptr);
        // T = P @ W1 + b1 ; T = relu(bn(T))
        gemm_bias<<<dim3(N_NODES / 64, 4), 256, 0, stream>>>(P, W1[L], b1[L], T, din);
        fzero<<<2, 256, 0, stream>>>(bnsums, 2 * HID);
        bn_stats<<<(N_NODES + 255) / 256, 256, 0, stream>>>(T, N_NODES, bnsums);
        bn_finalize<<<1, 256, 0, stream>>>(bnsums, g1[L], be1[L], rows_inv, bn_a, bn_c);
        bn_relu_apply<<<(n4 + 255) / 256, 256, 0, stream>>>((float4*)T, n4, bn_a, bn_c);
        // H = T @ W2 + b2 ; H = relu(bn(H))
        gemm_bias<<<dim3(N_NODES / 64, 4), 256, 0, stream>>>(T, W2[L], b2[L], H, HID);
        fzero<<<2, 256, 0, stream>>>(bnsums, 2 * HID);
        bn_stats<<<(N_NODES + 255) / 256, 256, 0, stream>>>(H, N_NODES, bnsums);
        bn_finalize<<<1, 256, 0, stream>>>(bnsums, bng[L], bnb[L], rows_inv, bn_a, bn_c);
        bn_relu_apply<<<(n4 + 255) / 256, 256, 0, stream>>>((float4*)H, n4, bn_a, bn_c);
        // hidden' = d_inv * H (H^T H_layer);  out_nodes (+)= hidden' @ headW[L]
        spmm_kernel<<<M_EDGES, HID, 0, stream>>>(off_e, idx_e, H, ebuf, nullptr);
        spmm_kernel<<<N_NODES, HID, 0, stream>>>(off_n, idx_n, ebuf, P, dinv);
        head_kernel<<<N_NODES / 4, 256, 0, stream>>>(P, headW + (size_t)L * HID * NCLS,
                                                     headb, onodes, L);
        hin = H;
        din = HID;
    }

    // per-graph mean readout
    fzero<<<(NG * NCLS + NG + 255) / 256, 256, 0, stream>>>(racc, NG * NCLS + NG);
    readout_accum<<<(N_NODES + 255) / 256, 256, 0, stream>>>(onodes, all_batch, racc, rcnt);
    readout_final<<<(NG * NCLS + 255) / 256, 256, 0, stream>>>(racc, rcnt, out);
}

// Round 2
// 752.714 us; speedup vs baseline: 2.0351x; 2.0351x over previous
//
#include <hip/hip_runtime.h>

#define N_NODES 40000
#define M_EDGES 10000
#define NNZ_CNT 400000
#define FT_DIM  128
#define HID     256
#define NCLS    10
#define NG      128
#define EPSV    1e-5f

typedef short s8v __attribute__((ext_vector_type(8)));
typedef float f4v __attribute__((ext_vector_type(4)));

__device__ __forceinline__ unsigned short f2bf(float x) {
    unsigned int u = __float_as_uint(x);
    u += 0x7fffu + ((u >> 16) & 1u);
    return (unsigned short)(u >> 16);
}
__device__ __forceinline__ float bf2f(unsigned short h) {
    return __uint_as_float(((unsigned int)h) << 16);
}

// ---------------- utility ----------------
__global__ void fzero(float* __restrict__ p, int n) {
    int i = blockIdx.x * 256 + threadIdx.x;
    if (i < n) p[i] = 0.f;
}

// ---------------- CSR build ----------------
__global__ void count_kernel(const int* __restrict__ ni, const int* __restrict__ ei,
                             int* __restrict__ cnt_e, int* __restrict__ cnt_n) {
    int i = blockIdx.x * 256 + threadIdx.x;
    if (i < NNZ_CNT) {
        atomicAdd(&cnt_e[ei[i]], 1);
        atomicAdd(&cnt_n[ni[i]], 1);
    }
}

// shuffle-based single-block exclusive scan, 4 elems/thread per 4096-chunk
__global__ __launch_bounds__(1024) void exscan_kernel(const int* __restrict__ in,
                                                      int* __restrict__ out, int n) {
    __shared__ int wsum[16];
    __shared__ int carry_s;
    int tid = threadIdx.x, lane = tid & 63, w = tid >> 6;
    if (tid == 0) carry_s = 0;
    __syncthreads();
    for (int base = 0; base < n; base += 4096) {
        int i0 = base + tid * 4;
        int v[4];
#pragma unroll
        for (int t = 0; t < 4; ++t) v[t] = (i0 + t < n) ? in[i0 + t] : 0;
        int s = v[0] + v[1] + v[2] + v[3];
        int sc = s;
#pragma unroll
        for (int d = 1; d < 64; d <<= 1) {
            int t = __shfl_up(sc, d, 64);
            if (lane >= d) sc += t;
        }
        if (lane == 63) wsum[w] = sc;
        __syncthreads();
        if (tid < 64) {
            int ws = (lane < 16) ? wsum[lane] : 0;
            int wsc = ws;
#pragma unroll
            for (int d = 1; d < 16; d <<= 1) {
                int t = __shfl_up(wsc, d, 64);
                if (lane >= d) wsc += t;
            }
            if (lane < 16) wsum[lane] = wsc - ws;  // exclusive wave offsets
        }
        __syncthreads();
        int carry = carry_s;
        int ex = carry + wsum[w] + (sc - s);
#pragma unroll
        for (int t = 0; t < 4; ++t) {
            if (i0 + t < n) out[i0 + t] = ex;
            ex += v[t];
        }
        __syncthreads();
        if (tid == 1023) carry_s = ex;   // = carry + chunk total
    }
    __syncthreads();
    if (tid == 0) out[n] = carry_s;
}

__global__ void fill_kernel(const int* __restrict__ ni, const int* __restrict__ ei,
                            const int* __restrict__ off_e, const int* __restrict__ off_n,
                            int* __restrict__ cur_e, int* __restrict__ cur_n,
                            int* __restrict__ idx_e, int* __restrict__ idx_n) {
    int i = blockIdx.x * 256 + threadIdx.x;
    if (i < NNZ_CNT) {
        int e = ei[i], n = ni[i];
        int pe = atomicAdd(&cur_e[e], 1);
        idx_e[off_e[e] + pe] = n;
        int pn = atomicAdd(&cur_n[n], 1);
        idx_n[off_n[n] + pn] = e;
    }
}

__global__ void dinv_kernel(const int* __restrict__ off_n, const int* __restrict__ idx_n,
                            const int* __restrict__ cnt_e, float* __restrict__ dinv) {
    int n = blockIdx.x * 256 + threadIdx.x;
    if (n < N_NODES) {
        int s = off_n[n], e = off_n[n + 1];
        float p = 0.f;
        for (int j = s; j < e; ++j) p += (float)cnt_e[idx_n[j]];
        dinv[n] = (p > 0.f) ? 1.0f / p : 1.0f;
    }
}

// ---------------- SpMM gather: one wave per row, VEC floats per lane ----------------
template<int VEC> struct VecT;
template<> struct VecT<2> { typedef float2 T; };
template<> struct VecT<4> { typedef float4 T; };

// out[r,:] = sum_{j in row r} xf(Y[idx[j],:]),  xf = relu(a*x+c) if XF
template<int VEC, bool XF>
__global__ __launch_bounds__(256) void spmm_gather(const int* __restrict__ off,
        const int* __restrict__ idx, const float* __restrict__ Y,
        const float* __restrict__ bna, const float* __restrict__ bnc,
        float* __restrict__ out) {
    typedef typename VecT<VEC>::T VT;
    const int D = VEC * 64;
    int lane = threadIdx.x & 63;
    int r = blockIdx.x * 4 + (threadIdx.x >> 6);
    int f0 = lane * VEC;
    int s = off[r], e = off[r + 1];
    float av[VEC], cv[VEC];
    if (XF) {
#pragma unroll
        for (int v = 0; v < VEC; ++v) { av[v] = bna[f0 + v]; cv[v] = bnc[f0 + v]; }
    }
    float acc0[VEC] = {}, acc1[VEC] = {}, acc2[VEC] = {}, acc3[VEC] = {};
    int j = s;
    for (; j + 4 <= e; j += 4) {
        int i0 = __builtin_amdgcn_readfirstlane(idx[j]);
        int i1 = __builtin_amdgcn_readfirstlane(idx[j + 1]);
        int i2 = __builtin_amdgcn_readfirstlane(idx[j + 2]);
        int i3 = __builtin_amdgcn_readfirstlane(idx[j + 3]);
        VT g0 = *(const VT*)(Y + (long)i0 * D + f0);
        VT g1 = *(const VT*)(Y + (long)i1 * D + f0);
        VT g2 = *(const VT*)(Y + (long)i2 * D + f0);
        VT g3 = *(const VT*)(Y + (long)i3 * D + f0);
        const float* p0 = (const float*)&g0;
        const float* p1 = (const float*)&g1;
        const float* p2 = (const float*)&g2;
        const float* p3 = (const float*)&g3;
#pragma unroll
        for (int v = 0; v < VEC; ++v) {
            float x0 = p0[v], x1 = p1[v], x2 = p2[v], x3 = p3[v];
            if (XF) {
                x0 = fmaxf(fmaf(av[v], x0, cv[v]), 0.f);
                x1 = fmaxf(fmaf(av[v], x1, cv[v]), 0.f);
                x2 = fmaxf(fmaf(av[v], x2, cv[v]), 0.f);
                x3 = fmaxf(fmaf(av[v], x3, cv[v]), 0.f);
            }
            acc0[v] += x0; acc1[v] += x1; acc2[v] += x2; acc3[v] += x3;
        }
    }
    for (; j < e; ++j) {
        int i0 = __builtin_amdgcn_readfirstlane(idx[j]);
        VT g0 = *(const VT*)(Y + (long)i0 * D + f0);
        const float* p0 = (const float*)&g0;
#pragma unroll
        for (int v = 0; v < VEC; ++v) {
            float x0 = p0[v];
            if (XF) x0 = fmaxf(fmaf(av[v], x0, cv[v]), 0.f);
            acc0[v] += x0;
        }
    }
    VT o; float* op = (float*)&o;
#pragma unroll
    for (int v = 0; v < VEC; ++v) op[v] = acc0[v] + acc1[v] + acc2[v] + acc3[v];
    *(VT*)(out + (long)r * D + f0) = o;
}

// node-side readout: P_row = dinv[r] * sum gathers; on[r,:] (+)= P_row @ Wh (+ hb)
__global__ __launch_bounds__(256) void spmm_head(const int* __restrict__ off,
        const int* __restrict__ idx, const float* __restrict__ Y,
        const float* __restrict__ dinv, const float* __restrict__ Wh,
        const float* __restrict__ hb, float* __restrict__ on, int mode) {
    int lane = threadIdx.x & 63;
    int r = blockIdx.x * 4 + (threadIdx.x >> 6);
    int f0 = lane * 4;
    int s = off[r], e = off[r + 1];
    float4 a0 = {0,0,0,0}, a1 = {0,0,0,0}, a2 = {0,0,0,0}, a3 = {0,0,0,0};
    int j = s;
    for (; j + 4 <= e; j += 4) {
        int i0 = __builtin_amdgcn_readfirstlane(idx[j]);
        int i1 = __builtin_amdgcn_readfirstlane(idx[j + 1]);
        int i2 = __builtin_amdgcn_readfirstlane(idx[j + 2]);
        int i3 = __builtin_amdgcn_readfirstlane(idx[j + 3]);
        float4 g0 = *(const float4*)(Y + (long)i0 * 256 + f0);
        float4 g1 = *(const float4*)(Y + (long)i1 * 256 + f0);
        float4 g2 = *(const float4*)(Y + (long)i2 * 256 + f0);
        float4 g3 = *(const float4*)(Y + (long)i3 * 256 + f0);
        a0.x += g0.x; a0.y += g0.y; a0.z += g0.z; a0.w += g0.w;
        a1.x += g1.x; a1.y += g1.y; a1.z += g1.z; a1.w += g1.w;
        a2.x += g2.x; a2.y += g2.y; a2.z += g2.z; a2.w += g2.w;
        a3.x += g3.x; a3.y += g3.y; a3.z += g3.z; a3.w += g3.w;
    }
    for (; j < e; ++j) {
        int i0 = __builtin_amdgcn_readfirstlane(idx[j]);
        float4 g0 = *(const float4*)(Y + (long)i0 * 256 + f0);
        a0.x += g0.x; a0.y += g0.y; a0.z += g0.z; a0.w += g0.w;
    }
    float di = dinv[r];
    float4 acc;
    acc.x = (a0.x + a1.x + a2.x + a3.x) * di;
    acc.y = (a0.y + a1.y + a2.y + a3.y) * di;
    acc.z = (a0.z + a1.z + a2.z + a3.z) * di;
    acc.w = (a0.w + a1.w + a2.w + a3.w) * di;
    const float* wp = Wh + (long)f0 * NCLS;
    float p[NCLS];
#pragma unroll
    for (int c = 0; c < NCLS; ++c)
        p[c] = acc.x * wp[c] + acc.y * wp[NCLS + c] + acc.z * wp[2 * NCLS + c]
             + acc.w * wp[3 * NCLS + c];
#pragma unroll
    for (int c = 0; c < NCLS; ++c) {
#pragma unroll
        for (int m = 1; m < 64; m <<= 1) p[c] += __shfl_xor(p[c], m, 64);
    }
    if (lane == 0) {
        if (mode == 0) {
#pragma unroll
            for (int c = 0; c < NCLS; ++c) on[(long)r * NCLS + c] = p[c] + hb[c];
        } else {
#pragma unroll
            for (int c = 0; c < NCLS; ++c) on[(long)r * NCLS + c] += p[c];
        }
    }
}

// ---------------- split-bf16 MFMA GEMM ----------------
// C[40000 x 256] = xf(A)[40000 x K] @ B[K x 256] + bias, xf = relu(bna*x+bnc) if XFORM.
// Fused column stats: stats[0:256] += colsum(C), stats[256:512] += colsumsq(C).
// Tile 64(M) x 128(N), K-step 32, 4 waves: wave w -> rows (w&1)*32, cols (w>>1)*64.
template<bool XFORM>
__global__ __launch_bounds__(256) void gemm_mfma(const float* __restrict__ A,
        const float* __restrict__ B, const float* __restrict__ bias,
        const float* __restrict__ bna, const float* __restrict__ bnc,
        float* __restrict__ C, float* __restrict__ stats, int K) {
    __shared__ __align__(16) unsigned short Ah[64][40], Al[64][40];
    __shared__ __align__(16) unsigned short Bh[128][40], Bl[128][40];
    __shared__ float lsum[128], lsq[128];
    int tid = threadIdx.x;
    int lane = tid & 63, w = tid >> 6;
    long row0 = (long)blockIdx.x * 64;
    int col0 = blockIdx.y * 128;
    int lm = lane & 15, lq = lane >> 4;
    int rw = (w & 1) * 32, cw = (w >> 1) * 64;
    int a_r = tid >> 3;            // 0..31
    int a_k = (tid & 7) * 4;       // 0,4,..,28
    int b_n = tid & 127;           // 0..127
    int b_k = (tid >> 7) * 16;     // 0 or 16
    f4v acc[2][4];
#pragma unroll
    for (int i = 0; i < 2; ++i)
#pragma unroll
        for (int j = 0; j < 4; ++j) acc[i][j] = (f4v){0.f, 0.f, 0.f, 0.f};
    if (tid < 128) { lsum[tid] = 0.f; lsq[tid] = 0.f; }

    for (int k0 = 0; k0 < K; k0 += 32) {
        // ---- stage A (64 x 32), fp32 -> bf16 hi/lo, optional BN+ReLU ----
        float4 ba4, bc4;
        if (XFORM) {
            ba4 = *(const float4*)(bna + k0 + a_k);
            bc4 = *(const float4*)(bnc + k0 + a_k);
        }
#pragma unroll
        for (int rr = 0; rr < 64; rr += 32) {
            int r = a_r + rr;
            float4 x = *(const float4*)(A + (row0 + r) * K + k0 + a_k);
            if (XFORM) {
                x.x = fmaxf(fmaf(ba4.x, x.x, bc4.x), 0.f);
                x.y = fmaxf(fmaf(ba4.y, x.y, bc4.y), 0.f);
                x.z = fmaxf(fmaf(ba4.z, x.z, bc4.z), 0.f);
                x.w = fmaxf(fmaf(ba4.w, x.w, bc4.w), 0.f);
            }
            unsigned short h0 = f2bf(x.x), h1 = f2bf(x.y), h2 = f2bf(x.z), h3 = f2bf(x.w);
            *(ushort4*)&Ah[r][a_k] = make_ushort4(h0, h1, h2, h3);
            *(ushort4*)&Al[r][a_k] = make_ushort4(f2bf(x.x - bf2f(h0)), f2bf(x.y - bf2f(h1)),
                                                  f2bf(x.z - bf2f(h2)), f2bf(x.w - bf2f(h3)));
        }
        // ---- stage B (32 x 128), transposed to [n][k] ----
        {
            unsigned short hb_[16], lb_[16];
#pragma unroll
            for (int kk = 0; kk < 16; ++kk) {
                float x = B[(long)(k0 + b_k + kk) * HID + col0 + b_n];
                unsigned short h = f2bf(x);
                hb_[kk] = h;
                lb_[kk] = f2bf(x - bf2f(h));
            }
#pragma unroll
            for (int q = 0; q < 16; q += 4) {
                *(ushort4*)&Bh[b_n][b_k + q] = make_ushort4(hb_[q], hb_[q+1], hb_[q+2], hb_[q+3]);
                *(ushort4*)&Bl[b_n][b_k + q] = make_ushort4(lb_[q], lb_[q+1], lb_[q+2], lb_[q+3]);
            }
        }
        __syncthreads();
        // ---- compute: 2 row-tiles x 4 col-tiles, triple-product split-bf16 ----
        s8v ah[2], al[2], bh[4], bl[4];
#pragma unroll
        for (int i = 0; i < 2; ++i) {
            ah[i] = *(const s8v*)&Ah[rw + i * 16 + lm][lq * 8];
            al[i] = *(const s8v*)&Al[rw + i * 16 + lm][lq * 8];
        }
#pragma unroll
        for (int j = 0; j < 4; ++j) {
            bh[j] = *(const s8v*)&Bh[cw + j * 16 + lm][lq * 8];
            bl[j] = *(const s8v*)&Bl[cw + j * 16 + lm][lq * 8];
        }
#pragma unroll
        for (int i = 0; i < 2; ++i)
#pragma unroll
            for (int j = 0; j < 4; ++j) {
                acc[i][j] = __builtin_amdgcn_mfma_f32_16x16x32_bf16(al[i], bh[j], acc[i][j], 0, 0, 0);
                acc[i][j] = __builtin_amdgcn_mfma_f32_16x16x32_bf16(ah[i], bl[j], acc[i][j], 0, 0, 0);
                acc[i][j] = __builtin_amdgcn_mfma_f32_16x16x32_bf16(ah[i], bh[j], acc[i][j], 0, 0, 0);
            }
        __syncthreads();
    }
    // ---- epilogue: bias, store, fused column stats ----
#pragma unroll
    for (int j = 0; j < 4; ++j) {
        int lc = cw + j * 16 + lm;        // local col 0..127
        int col = col0 + lc;
        float bsv = bias[col];
        float s = 0.f, sq = 0.f;
#pragma unroll
        for (int i = 0; i < 2; ++i) {
#pragma unroll
            for (int reg = 0; reg < 4; ++reg) {
                long row = row0 + rw + i * 16 + lq * 4 + reg;
                float v = acc[i][j][reg] + bsv;
                C[row * HID + col] = v;
                s += v;
                sq += v * v;
            }
        }
        atomicAdd(&lsum[lc], s);
        atomicAdd(&lsq[lc], sq);
    }
    __syncthreads();
    if (tid < 128) {
        atomicAdd(&stats[col0 + tid], lsum[tid]);
        atomicAdd(&stats[HID + col0 + tid], lsq[tid]);
    }
}

__global__ void bn_finalize(const float* __restrict__ stats, const float* __restrict__ g,
                            const float* __restrict__ be, float rows_inv,
                            float* __restrict__ a, float* __restrict__ c) {
    int f = threadIdx.x;   // 256 threads
    float mean = stats[f] * rows_inv;
    float var = stats[HID + f] * rows_inv - mean * mean;
    float av = g[f] * rsqrtf(var + EPSV);
    a[f] = av;
    c[f] = be[f] - mean * av;
}

// ---------------- readout: per-graph mean ----------------
__global__ __launch_bounds__(256) void readout_accum(const float* __restrict__ on,
                                                     const int* __restrict__ ab,
                                                     float* __restrict__ racc,
                                                     float* __restrict__ rcnt) {
    __shared__ float lacc[NG * NCLS];
    __shared__ float lcnt[NG];
    int tid = threadIdx.x;
    for (int i = tid; i < NG * NCLS; i += 256) lacc[i] = 0.f;
    if (tid < NG) lcnt[tid] = 0.f;
    __syncthreads();
    int n = blockIdx.x * 256 + tid;
    if (n < N_NODES) {
        int b = ab[n];
        atomicAdd(&lcnt[b], 1.0f);
        for (int c = 0; c < NCLS; ++c) atomicAdd(&lacc[b * NCLS + c], on[(long)n * NCLS + c]);
    }
    __syncthreads();
    if (tid < NG && lcnt[tid] > 0.f) {
        atomicAdd(&rcnt[tid], lcnt[tid]);
        for (int c = 0; c < NCLS; ++c) atomicAdd(&racc[tid * NCLS + c], lacc[tid * NCLS + c]);
    }
}

__global__ void readout_final(const float* __restrict__ racc, const float* __restrict__ rcnt,
                              float* __restrict__ out) {
    int i = blockIdx.x * 256 + threadIdx.x;
    if (i < NG * NCLS) out[i] = racc[i] / fmaxf(rcnt[i / NCLS], 1.0f);
}

// ---------------- launch ----------------
extern "C" void kernel_launch(void* const* d_in, const int* in_sizes, int n_in,
                              void* d_out, int out_size, void* d_ws, size_t ws_size,
                              hipStream_t stream) {
    const float* X         = (const float*)d_in[0];
    const int*   node_idx  = (const int*)d_in[1];
    const int*   edge_idx  = (const int*)d_in[2];
    const int*   all_batch = (const int*)d_in[3];
    const float* W1[2]  = {(const float*)d_in[4],  (const float*)d_in[12]};
    const float* b1[2]  = {(const float*)d_in[5],  (const float*)d_in[13]};
    const float* g1[2]  = {(const float*)d_in[6],  (const float*)d_in[14]};
    const float* be1[2] = {(const float*)d_in[7],  (const float*)d_in[15]};
    const float* W2[2]  = {(const float*)d_in[8],  (const float*)d_in[16]};
    const float* b2[2]  = {(const float*)d_in[9],  (const float*)d_in[17]};
    const float* bng[2] = {(const float*)d_in[10], (const float*)d_in[18]};
    const float* bnb[2] = {(const float*)d_in[11], (const float*)d_in[19]};
    const float* headW  = (const float*)d_in[20];
    const float* headb  = (const float*)d_in[21];
    float* out = (float*)d_out;

    char* base = (char*)d_ws;
    size_t off = 0;
    auto alloc = [&](size_t bytes) -> void* {
        size_t o = (off + 255) & ~(size_t)255;
        off = o + bytes;
        return (void*)(base + o);
    };

    // one contiguous zero region: counts/cursors + stats + racc + rcnt
    const int ZINTS = 2 * M_EDGES + 2 * N_NODES;           // 100000
    const int ZTOT  = ZINTS + 4 * 2 * HID + NG * NCLS + NG; // 100000+2048+1280+128
    int* ibase  = (int*)alloc((size_t)ZTOT * 4);
    int* cnt_e  = ibase;
    int* cnt_n  = cnt_e + M_EDGES;
    int* cur_e  = cnt_n + N_NODES;
    int* cur_n  = cur_e + M_EDGES;
    float* statsall = (float*)(ibase + ZINTS);             // 4 stages x 512
    float* racc     = statsall + 4 * 2 * HID;              // 1280
    float* rcnt     = racc + NG * NCLS;                    // 128

    int* off_e  = (int*)alloc((M_EDGES + 1) * 4);
    int* off_n  = (int*)alloc((N_NODES + 1) * 4);
    int* idx_e  = (int*)alloc((size_t)NNZ_CNT * 4);
    int* idx_n  = (int*)alloc((size_t)NNZ_CNT * 4);
    float* dinv = (float*)alloc((size_t)N_NODES * 4);
    float* ebuf = (float*)alloc((size_t)M_EDGES * HID * 4);
    float* P    = (float*)alloc((size_t)N_NODES * HID * 4);
    float* T    = (float*)alloc((size_t)N_NODES * HID * 4);
    float* H    = (float*)alloc((size_t)N_NODES * HID * 4);
    float* onodes = (float*)alloc((size_t)N_NODES * NCLS * 4);
    float* bnA  = (float*)alloc(4 * HID * 4);
    float* bnC  = (float*)alloc(4 * HID * 4);

    const int nnz_blocks = (NNZ_CNT + 255) / 256;
    const float rows_inv = 1.0f / (float)N_NODES;

    // --- CSR build + degree norm ---
    fzero<<<(ZTOT + 255) / 256, 256, 0, stream>>>((float*)ibase, ZTOT);
    count_kernel<<<nnz_blocks, 256, 0, stream>>>(node_idx, edge_idx, cnt_e, cnt_n);
    exscan_kernel<<<1, 1024, 0, stream>>>(cnt_e, off_e, M_EDGES);
    exscan_kernel<<<1, 1024, 0, stream>>>(cnt_n, off_n, N_NODES);
    fill_kernel<<<nnz_blocks, 256, 0, stream>>>(node_idx, edge_idx, off_e, off_n,
                                                cur_e, cur_n, idx_e, idx_n);
    dinv_kernel<<<(N_NODES + 255) / 256, 256, 0, stream>>>(off_n, idx_n, cnt_e, dinv);

    const dim3 ggrid(N_NODES / 64, 2);

    // ---------------- layer 0 ----------------
    spmm_gather<2, false><<<M_EDGES / 4, 256, 0, stream>>>(off_e, idx_e, X, nullptr, nullptr, ebuf);
    spmm_gather<2, false><<<N_NODES / 4, 256, 0, stream>>>(off_n, idx_n, ebuf, nullptr, nullptr, P);
    gemm_mfma<false><<<ggrid, 256, 0, stream>>>(P, W1[0], b1[0], nullptr, nullptr,
                                                T, statsall + 0 * 512, FT_DIM);
    bn_finalize<<<1, 256, 0, stream>>>(statsall + 0 * 512, g1[0], be1[0], rows_inv,
                                       bnA + 0 * HID, bnC + 0 * HID);
    gemm_mfma<true><<<ggrid, 256, 0, stream>>>(T, W2[0], b2[0], bnA + 0 * HID, bnC + 0 * HID,
                                               H, statsall + 1 * 512, HID);
    bn_finalize<<<1, 256, 0, stream>>>(statsall + 1 * 512, bng[0], bnb[0], rows_inv,
                                       bnA + 1 * HID, bnC + 1 * HID);
    // shared edge pass: ebuf = H^T @ relu(bn(H0_raw))  (layer-0 readout AND layer-1 pooling)
    spmm_gather<4, true><<<M_EDGES / 4, 256, 0, stream>>>(off_e, idx_e, H,
                                                          bnA + 1 * HID, bnC + 1 * HID, ebuf);
    spmm_head<<<N_NODES / 4, 256, 0, stream>>>(off_n, idx_n, ebuf, dinv, headW, headb, onodes, 0);
    spmm_gather<4, false><<<N_NODES / 4, 256, 0, stream>>>(off_n, idx_n, ebuf, nullptr, nullptr, P);

    // ---------------- layer 1 ----------------
    gemm_mfma<false><<<ggrid, 256, 0, stream>>>(P, W1[1], b1[1], nullptr, nullptr,
                                                T, statsall + 2 * 512, HID);
    bn_finalize<<<1, 256, 0, stream>>>(statsall + 2 * 512, g1[1], be1[1], rows_inv,
                                       bnA + 2 * HID, bnC + 2 * HID);
    gemm_mfma<true><<<ggrid, 256, 0, stream>>>(T, W2[1], b2[1], bnA + 2 * HID, bnC + 2 * HID,
                                               H, statsall + 3 * 512, HID);
    bn_finalize<<<1, 256, 0, stream>>>(statsall + 3 * 512, bng[1], bnb[1], rows_inv,
                                       bnA + 3 * HID, bnC + 3 * HID);
    spmm_gather<4, true><<<M_EDGES / 4, 256, 0, stream>>>(off_e, idx_e, H,
                                                          bnA + 3 * HID, bnC + 3 * HID, ebuf);
    spmm_head<<<N_NODES / 4, 256, 0, stream>>>(off_n, idx_n, ebuf, dinv,
                                               headW + (size_t)HID * NCLS, headb, onodes, 1);

    // ---------------- readout ----------------
    readout_accum<<<(N_NODES + 255) / 256, 256, 0, stream>>>(onodes, all_batch, racc, rcnt);
    readout_final<<<(NG * NCLS + 255) / 256, 256, 0, stream>>>(racc, rcnt, out);
}

// Round 3
// 731.703 us; speedup vs baseline: 2.0936x; 1.0287x over previous
//
#include <hip/hip_runtime.h>

#define N_NODES 40000
#define M_EDGES 10000
#define NNZ_CNT 400000
#define FT_DIM  128
#define HID     256
#define NCLS    10
#define NG      128
#define EPSV    1e-5f

typedef short s8v __attribute__((ext_vector_type(8)));
typedef float f4v __attribute__((ext_vector_type(4)));
typedef unsigned short u2v __attribute__((ext_vector_type(2)));
typedef unsigned short u4v __attribute__((ext_vector_type(4)));

__device__ __forceinline__ unsigned short f2bf(float x) {
    unsigned int u = __float_as_uint(x);
    u += 0x7fffu + ((u >> 16) & 1u);
    return (unsigned short)(u >> 16);
}
__device__ __forceinline__ float bf2f(unsigned short h) {
    return __uint_as_float(((unsigned int)h) << 16);
}

// ---------------- utility ----------------
__global__ void fzero(float* __restrict__ p, int n) {
    int i = blockIdx.x * 256 + threadIdx.x;
    if (i < n) p[i] = 0.f;
}

// ---------------- CSR build ----------------
__global__ void count_kernel(const int* __restrict__ ni, const int* __restrict__ ei,
                             int* __restrict__ cnt_e, int* __restrict__ cnt_n) {
    int i = blockIdx.x * 256 + threadIdx.x;
    if (i < NNZ_CNT) {
        atomicAdd(&cnt_e[ei[i]], 1);
        atomicAdd(&cnt_n[ni[i]], 1);
    }
}

__global__ __launch_bounds__(1024) void exscan_kernel(const int* __restrict__ in,
                                                      int* __restrict__ out, int n) {
    __shared__ int wsum[16];
    __shared__ int carry_s;
    int tid = threadIdx.x, lane = tid & 63, w = tid >> 6;
    if (tid == 0) carry_s = 0;
    __syncthreads();
    for (int base = 0; base < n; base += 4096) {
        int i0 = base + tid * 4;
        int v[4];
#pragma unroll
        for (int t = 0; t < 4; ++t) v[t] = (i0 + t < n) ? in[i0 + t] : 0;
        int s = v[0] + v[1] + v[2] + v[3];
        int sc = s;
#pragma unroll
        for (int d = 1; d < 64; d <<= 1) {
            int t = __shfl_up(sc, d, 64);
            if (lane >= d) sc += t;
        }
        if (lane == 63) wsum[w] = sc;
        __syncthreads();
        if (tid < 64) {
            int ws = (lane < 16) ? wsum[lane] : 0;
            int wsc = ws;
#pragma unroll
            for (int d = 1; d < 16; d <<= 1) {
                int t = __shfl_up(wsc, d, 64);
                if (lane >= d) wsc += t;
            }
            if (lane < 16) wsum[lane] = wsc - ws;
        }
        __syncthreads();
        int carry = carry_s;
        int ex = carry + wsum[w] + (sc - s);
#pragma unroll
        for (int t = 0; t < 4; ++t) {
            if (i0 + t < n) out[i0 + t] = ex;
            ex += v[t];
        }
        __syncthreads();
        if (tid == 1023) carry_s = ex;
    }
    __syncthreads();
    if (tid == 0) out[n] = carry_s;
}

__global__ void fill_kernel(const int* __restrict__ ni, const int* __restrict__ ei,
                            const int* __restrict__ off_e, const int* __restrict__ off_n,
                            int* __restrict__ cur_e, int* __restrict__ cur_n,
                            int* __restrict__ idx_e, int* __restrict__ idx_n) {
    int i = blockIdx.x * 256 + threadIdx.x;
    if (i < NNZ_CNT) {
        int e = ei[i], n = ni[i];
        int pe = atomicAdd(&cur_e[e], 1);
        idx_e[off_e[e] + pe] = n;
        int pn = atomicAdd(&cur_n[n], 1);
        idx_n[off_n[n] + pn] = e;
    }
}

__global__ void dinv_kernel(const int* __restrict__ off_n, const int* __restrict__ idx_n,
                            const int* __restrict__ cnt_e, float* __restrict__ dinv) {
    int n = blockIdx.x * 256 + threadIdx.x;
    if (n < N_NODES) {
        int s = off_n[n], e = off_n[n + 1];
        float p = 0.f;
        for (int j = s; j < e; ++j) p += (float)cnt_e[idx_n[j]];
        dinv[n] = (p > 0.f) ? 1.0f / p : 1.0f;
    }
}

// ---------------- weight prep: W[K x 256] fp32 -> planes [256 cols][K] bf16 hi/lo ----------------
__global__ void wprep(const float* __restrict__ W, unsigned short* __restrict__ bh,
                      unsigned short* __restrict__ bl, int K) {
    int i = blockIdx.x * 256 + threadIdx.x;
    if (i < K * 256) {
        int k = i >> 8, c = i & 255;
        float x = W[i];
        unsigned short h = f2bf(x);
        bh[c * K + k] = h;
        bl[c * K + k] = f2bf(x - bf2f(h));
    }
}

// ---------------- fp32 -> bf16 plane (round only) ----------------
__global__ void fsplit(const float4* __restrict__ src, u4v* __restrict__ h, int n4) {
    int i = blockIdx.x * 256 + threadIdx.x;
    if (i < n4) {
        float4 v = src[i];
        h[i] = (u4v){f2bf(v.x), f2bf(v.y), f2bf(v.z), f2bf(v.w)};
    }
}

// ---------------- relu(bn(x)) -> bf16 plane(s) ----------------
template<bool DUAL>
__global__ __launch_bounds__(256) void bn_split(const float4* __restrict__ src,
        const float* __restrict__ a, const float* __restrict__ c,
        u4v* __restrict__ hOut, u4v* __restrict__ lOut, int n4) {
    int i = blockIdx.x * 256 + threadIdx.x;
    if (i >= n4) return;
    int col = (i << 2) & (HID - 1);
    float4 av = *(const float4*)(a + col);
    float4 cv = *(const float4*)(c + col);
    float4 v = src[i];
    float x0 = fmaxf(fmaf(av.x, v.x, cv.x), 0.f);
    float x1 = fmaxf(fmaf(av.y, v.y, cv.y), 0.f);
    float x2 = fmaxf(fmaf(av.z, v.z, cv.z), 0.f);
    float x3 = fmaxf(fmaf(av.w, v.w, cv.w), 0.f);
    u4v h = (u4v){f2bf(x0), f2bf(x1), f2bf(x2), f2bf(x3)};
    hOut[i] = h;
    if (DUAL) {
        lOut[i] = (u4v){f2bf(x0 - bf2f(h[0])), f2bf(x1 - bf2f(h[1])),
                        f2bf(x2 - bf2f(h[2])), f2bf(x3 - bf2f(h[3]))};
    }
}

// ---------------- gathers over bf16 source, fp32 accumulation ----------------
template<int VEC> struct SV;
template<> struct SV<2> { typedef u2v T; };
template<> struct SV<4> { typedef u4v T; };

// PLANES: write fp32 sum split to hi/lo planes; else write rounded bf16 sum
template<int VEC, bool PLANES>
__global__ __launch_bounds__(256) void gather_pool(const int* __restrict__ off,
        const int* __restrict__ idx, const unsigned short* __restrict__ Y,
        unsigned short* __restrict__ outh, unsigned short* __restrict__ outl) {
    typedef typename SV<VEC>::T VT;
    const int D = VEC * 64;
    int lane = threadIdx.x & 63;
    int r = blockIdx.x * 4 + (threadIdx.x >> 6);
    int f0 = lane * VEC;
    int s = off[r], e = off[r + 1];
    float acc0[VEC] = {}, acc1[VEC] = {}, acc2[VEC] = {}, acc3[VEC] = {};
    int j = s;
    for (; j + 4 <= e; j += 4) {
        int i0 = __builtin_amdgcn_readfirstlane(idx[j]);
        int i1 = __builtin_amdgcn_readfirstlane(idx[j + 1]);
        int i2 = __builtin_amdgcn_readfirstlane(idx[j + 2]);
        int i3 = __builtin_amdgcn_readfirstlane(idx[j + 3]);
        VT g0 = *(const VT*)(Y + (long)i0 * D + f0);
        VT g1 = *(const VT*)(Y + (long)i1 * D + f0);
        VT g2 = *(const VT*)(Y + (long)i2 * D + f0);
        VT g3 = *(const VT*)(Y + (long)i3 * D + f0);
#pragma unroll
        for (int v = 0; v < VEC; ++v) {
            acc0[v] += bf2f(g0[v]); acc1[v] += bf2f(g1[v]);
            acc2[v] += bf2f(g2[v]); acc3[v] += bf2f(g3[v]);
        }
    }
    for (; j < e; ++j) {
        int i0 = __builtin_amdgcn_readfirstlane(idx[j]);
        VT g0 = *(const VT*)(Y + (long)i0 * D + f0);
#pragma unroll
        for (int v = 0; v < VEC; ++v) acc0[v] += bf2f(g0[v]);
    }
    VT h, l;
#pragma unroll
    for (int v = 0; v < VEC; ++v) {
        float sum = acc0[v] + acc1[v] + acc2[v] + acc3[v];
        unsigned short hh = f2bf(sum);
        h[v] = hh;
        if (PLANES) l[v] = f2bf(sum - bf2f(hh));
    }
    *(VT*)(outh + (long)r * D + f0) = h;
    if (PLANES) *(VT*)(outl + (long)r * D + f0) = l;
}

// node-side: pooled sum (optionally -> P planes) + head matmul on dinv-scaled sum
template<bool WRITE_P>
__global__ __launch_bounds__(256) void gather_head(const int* __restrict__ off,
        const int* __restrict__ idx, const unsigned short* __restrict__ Y,
        const float* __restrict__ dinv, const float* __restrict__ Wh,
        const float* __restrict__ hb, float* __restrict__ on,
        unsigned short* __restrict__ Ph, unsigned short* __restrict__ Pl) {
    int lane = threadIdx.x & 63;
    int r = blockIdx.x * 4 + (threadIdx.x >> 6);
    int f0 = lane * 4;
    int s = off[r], e = off[r + 1];
    float acc0[4] = {}, acc1[4] = {}, acc2[4] = {}, acc3[4] = {};
    int j = s;
    for (; j + 4 <= e; j += 4) {
        int i0 = __builtin_amdgcn_readfirstlane(idx[j]);
        int i1 = __builtin_amdgcn_readfirstlane(idx[j + 1]);
        int i2 = __builtin_amdgcn_readfirstlane(idx[j + 2]);
        int i3 = __builtin_amdgcn_readfirstlane(idx[j + 3]);
        u4v g0 = *(const u4v*)(Y + (long)i0 * 256 + f0);
        u4v g1 = *(const u4v*)(Y + (long)i1 * 256 + f0);
        u4v g2 = *(const u4v*)(Y + (long)i2 * 256 + f0);
        u4v g3 = *(const u4v*)(Y + (long)i3 * 256 + f0);
#pragma unroll
        for (int v = 0; v < 4; ++v) {
            acc0[v] += bf2f(g0[v]); acc1[v] += bf2f(g1[v]);
            acc2[v] += bf2f(g2[v]); acc3[v] += bf2f(g3[v]);
        }
    }
    for (; j < e; ++j) {
        int i0 = __builtin_amdgcn_readfirstlane(idx[j]);
        u4v g0 = *(const u4v*)(Y + (long)i0 * 256 + f0);
#pragma unroll
        for (int v = 0; v < 4; ++v) acc0[v] += bf2f(g0[v]);
    }
    float sum[4];
#pragma unroll
    for (int v = 0; v < 4; ++v) sum[v] = acc0[v] + acc1[v] + acc2[v] + acc3[v];
    if (WRITE_P) {
        u4v h, l;
#pragma unroll
        for (int v = 0; v < 4; ++v) {
            unsigned short hh = f2bf(sum[v]);
            h[v] = hh;
            l[v] = f2bf(sum[v] - bf2f(hh));
        }
        *(u4v*)(Ph + (long)r * 256 + f0) = h;
        *(u4v*)(Pl + (long)r * 256 + f0) = l;
    }
    float di = dinv[r];
    const float* wp = Wh + (long)f0 * NCLS;
    float p[NCLS];
#pragma unroll
    for (int c = 0; c < NCLS; ++c)
        p[c] = di * (sum[0] * wp[c] + sum[1] * wp[NCLS + c] + sum[2] * wp[2 * NCLS + c]
                   + sum[3] * wp[3 * NCLS + c]);
#pragma unroll
    for (int c = 0; c < NCLS; ++c) {
#pragma unroll
        for (int m = 1; m < 64; m <<= 1) p[c] += __shfl_xor(p[c], m, 64);
    }
    if (lane == 0) {
        if (WRITE_P) {
#pragma unroll
            for (int c = 0; c < NCLS; ++c) on[(long)r * NCLS + c] = p[c] + hb[c];
        } else {
#pragma unroll
            for (int c = 0; c < NCLS; ++c) on[(long)r * NCLS + c] += p[c];
        }
    }
}

// ---------------- split-bf16 MFMA GEMM, pure-copy staging ----------------
// C[40000 x 256] = (Ah+Al)[40000 x K] @ (Bh+Bl)[K x 256] + bias  (A planes row-major [row][k],
// B planes [col][k]); fused column stats. Tile 64x128, K-step 32.
__global__ __launch_bounds__(256) void gemm_pc(const unsigned short* __restrict__ Ahg,
        const unsigned short* __restrict__ Alg, const unsigned short* __restrict__ Bhg,
        const unsigned short* __restrict__ Blg, const float* __restrict__ bias,
        float* __restrict__ C, float* __restrict__ stats, int K) {
    __shared__ __align__(16) unsigned short As[2][64][40];
    __shared__ __align__(16) unsigned short Bs[2][128][40];
    __shared__ float lsum[128], lsq[128];
    int tid = threadIdx.x;
    int lane = tid & 63, w = tid >> 6;
    long row0 = (long)blockIdx.x * 64;
    int col0 = blockIdx.y * 128;
    int lm = lane & 15, lq = lane >> 4;
    int rw = (w & 1) * 32, cw = (w >> 1) * 64;
    // A staging: plane = tid>>7, row = (tid&127)>>1, half = tid&1 (16 shorts each)
    int ap = tid >> 7, ar = (tid & 127) >> 1, ah_ = tid & 1;
    // B staging: plane = tid>>7, col = tid&127 (32 shorts each)
    int bp = tid >> 7, bc = tid & 127;
    const unsigned short* Aplane = ap ? Alg : Ahg;
    const unsigned short* Bplane = bp ? Blg : Bhg;
    const unsigned short* asrc0 = Aplane + (row0 + ar) * (long)K + ah_ * 16;
    const unsigned short* bsrc0 = Bplane + (long)(col0 + bc) * K;
    f4v acc[2][4];
#pragma unroll
    for (int i = 0; i < 2; ++i)
#pragma unroll
        for (int j = 0; j < 4; ++j) acc[i][j] = (f4v){0.f, 0.f, 0.f, 0.f};
    if (tid < 128) { lsum[tid] = 0.f; lsq[tid] = 0.f; }

    for (int k0 = 0; k0 < K; k0 += 32) {
        s8v a0 = *(const s8v*)(asrc0 + k0);
        s8v a1 = *(const s8v*)(asrc0 + k0 + 8);
        s8v b0 = *(const s8v*)(bsrc0 + k0);
        s8v b1 = *(const s8v*)(bsrc0 + k0 + 8);
        s8v b2 = *(const s8v*)(bsrc0 + k0 + 16);
        s8v b3 = *(const s8v*)(bsrc0 + k0 + 24);
        *(s8v*)&As[ap][ar][ah_ * 16]     = a0;
        *(s8v*)&As[ap][ar][ah_ * 16 + 8] = a1;
        *(s8v*)&Bs[bp][bc][0]  = b0;
        *(s8v*)&Bs[bp][bc][8]  = b1;
        *(s8v*)&Bs[bp][bc][16] = b2;
        *(s8v*)&Bs[bp][bc][24] = b3;
        __syncthreads();
        s8v ah[2], al[2], bh[4], bl[4];
#pragma unroll
        for (int i = 0; i < 2; ++i) {
            ah[i] = *(const s8v*)&As[0][rw + i * 16 + lm][lq * 8];
            al[i] = *(const s8v*)&As[1][rw + i * 16 + lm][lq * 8];
        }
#pragma unroll
        for (int j = 0; j < 4; ++j) {
            bh[j] = *(const s8v*)&Bs[0][cw + j * 16 + lm][lq * 8];
            bl[j] = *(const s8v*)&Bs[1][cw + j * 16 + lm][lq * 8];
        }
#pragma unroll
        for (int i = 0; i < 2; ++i)
#pragma unroll
            for (int j = 0; j < 4; ++j) {
                acc[i][j] = __builtin_amdgcn_mfma_f32_16x16x32_bf16(al[i], bh[j], acc[i][j], 0, 0, 0);
                acc[i][j] = __builtin_amdgcn_mfma_f32_16x16x32_bf16(ah[i], bl[j], acc[i][j], 0, 0, 0);
                acc[i][j] = __builtin_amdgcn_mfma_f32_16x16x32_bf16(ah[i], bh[j], acc[i][j], 0, 0, 0);
            }
        __syncthreads();
    }
#pragma unroll
    for (int j = 0; j < 4; ++j) {
        int lc = cw + j * 16 + lm;
        int col = col0 + lc;
        float bsv = bias[col];
        float s = 0.f, sq = 0.f;
#pragma unroll
        for (int i = 0; i < 2; ++i) {
#pragma unroll
            for (int reg = 0; reg < 4; ++reg) {
                long row = row0 + rw + i * 16 + lq * 4 + reg;
                float v = acc[i][j][reg] + bsv;
                C[row * HID + col] = v;
                s += v;
                sq += v * v;
            }
        }
        atomicAdd(&lsum[lc], s);
        atomicAdd(&lsq[lc], sq);
    }
    __syncthreads();
    if (tid < 128) {
        atomicAdd(&stats[col0 + tid], lsum[tid]);
        atomicAdd(&stats[HID + col0 + tid], lsq[tid]);
    }
}

__global__ void bn_finalize(const float* __restrict__ stats, const float* __restrict__ g,
                            const float* __restrict__ be, float rows_inv,
                            float* __restrict__ a, float* __restrict__ c) {
    int f = threadIdx.x;
    float mean = stats[f] * rows_inv;
    float var = stats[HID + f] * rows_inv - mean * mean;
    float av = g[f] * rsqrtf(var + EPSV);
    a[f] = av;
    c[f] = be[f] - mean * av;
}

// ---------------- readout ----------------
__global__ __launch_bounds__(256) void readout_accum(const float* __restrict__ on,
                                                     const int* __restrict__ ab,
                                                     float* __restrict__ racc,
                                                     float* __restrict__ rcnt) {
    __shared__ float lacc[NG * NCLS];
    __shared__ float lcnt[NG];
    int tid = threadIdx.x;
    for (int i = tid; i < NG * NCLS; i += 256) lacc[i] = 0.f;
    if (tid < NG) lcnt[tid] = 0.f;
    __syncthreads();
    int n = blockIdx.x * 256 + tid;
    if (n < N_NODES) {
        int b = ab[n];
        atomicAdd(&lcnt[b], 1.0f);
        for (int c = 0; c < NCLS; ++c) atomicAdd(&lacc[b * NCLS + c], on[(long)n * NCLS + c]);
    }
    __syncthreads();
    if (tid < NG && lcnt[tid] > 0.f) {
        atomicAdd(&rcnt[tid], lcnt[tid]);
        for (int c = 0; c < NCLS; ++c) atomicAdd(&racc[tid * NCLS + c], lacc[tid * NCLS + c]);
    }
}

__global__ void readout_final(const float* __restrict__ racc, const float* __restrict__ rcnt,
                              float* __restrict__ out) {
    int i = blockIdx.x * 256 + threadIdx.x;
    if (i < NG * NCLS) out[i] = racc[i] / fmaxf(rcnt[i / NCLS], 1.0f);
}

// ---------------- launch ----------------
extern "C" void kernel_launch(void* const* d_in, const int* in_sizes, int n_in,
                              void* d_out, int out_size, void* d_ws, size_t ws_size,
                              hipStream_t stream) {
    const float* X         = (const float*)d_in[0];
    const int*   node_idx  = (const int*)d_in[1];
    const int*   edge_idx  = (const int*)d_in[2];
    const int*   all_batch = (const int*)d_in[3];
    const float* W1[2]  = {(const float*)d_in[4],  (const float*)d_in[12]};
    const float* b1[2]  = {(const float*)d_in[5],  (const float*)d_in[13]};
    const float* g1[2]  = {(const float*)d_in[6],  (const float*)d_in[14]};
    const float* be1[2] = {(const float*)d_in[7],  (const float*)d_in[15]};
    const float* W2[2]  = {(const float*)d_in[8],  (const float*)d_in[16]};
    const float* b2[2]  = {(const float*)d_in[9],  (const float*)d_in[17]};
    const float* bng[2] = {(const float*)d_in[10], (const float*)d_in[18]};
    const float* bnb[2] = {(const float*)d_in[11], (const float*)d_in[19]};
    const float* headW  = (const float*)d_in[20];
    const float* headb  = (const float*)d_in[21];
    float* out = (float*)d_out;

    char* base = (char*)d_ws;
    size_t off = 0;
    auto alloc = [&](size_t bytes) -> void* {
        size_t o = (off + 255) & ~(size_t)255;
        off = o + bytes;
        return (void*)(base + o);
    };

    const int ZINTS = 2 * M_EDGES + 2 * N_NODES;
    const int ZTOT  = ZINTS + 4 * 2 * HID + NG * NCLS + NG;
    int* ibase  = (int*)alloc((size_t)ZTOT * 4);
    int* cnt_e  = ibase;
    int* cnt_n  = cnt_e + M_EDGES;
    int* cur_e  = cnt_n + N_NODES;
    int* cur_n  = cur_e + M_EDGES;
    float* statsall = (float*)(ibase + ZINTS);
    float* racc     = statsall + 4 * 2 * HID;
    float* rcnt     = racc + NG * NCLS;

    int* off_e  = (int*)alloc((M_EDGES + 1) * 4);
    int* off_n  = (int*)alloc((N_NODES + 1) * 4);
    int* idx_e  = (int*)alloc((size_t)NNZ_CNT * 4);
    int* idx_n  = (int*)alloc((size_t)NNZ_CNT * 4);
    float* dinv = (float*)alloc((size_t)N_NODES * 4);

    unsigned short* Xb = (unsigned short*)alloc((size_t)N_NODES * FT_DIM * 2);
    unsigned short* Eb = (unsigned short*)alloc((size_t)M_EDGES * HID * 2);
    unsigned short* Ph = (unsigned short*)alloc((size_t)N_NODES * HID * 2);
    unsigned short* Pl = (unsigned short*)alloc((size_t)N_NODES * HID * 2);
    unsigned short* Ahp = (unsigned short*)alloc((size_t)N_NODES * HID * 2);
    unsigned short* Alp = (unsigned short*)alloc((size_t)N_NODES * HID * 2);
    unsigned short* Hb  = (unsigned short*)alloc((size_t)N_NODES * HID * 2);
    float* T      = (float*)alloc((size_t)N_NODES * HID * 4);   // also reused as Hf
    float* onodes = (float*)alloc((size_t)N_NODES * NCLS * 4);
    // weight planes
    unsigned short* Wp[4][2];
    int WK[4] = {FT_DIM, HID, HID, HID};
    for (int m = 0; m < 4; ++m) {
        Wp[m][0] = (unsigned short*)alloc((size_t)WK[m] * HID * 2);
        Wp[m][1] = (unsigned short*)alloc((size_t)WK[m] * HID * 2);
    }
    float* bnA = (float*)alloc(4 * HID * 4);
    float* bnC = (float*)alloc(4 * HID * 4);

    const int nnz_blocks = (NNZ_CNT + 255) / 256;
    const float rows_inv = 1.0f / (float)N_NODES;
    const int n4 = N_NODES * HID / 4;
    const dim3 ggrid(N_NODES / 64, 2);

    // --- CSR build + degree norm + weight prep ---
    fzero<<<(ZTOT + 255) / 256, 256, 0, stream>>>((float*)ibase, ZTOT);
    count_kernel<<<nnz_blocks, 256, 0, stream>>>(node_idx, edge_idx, cnt_e, cnt_n);
    exscan_kernel<<<1, 1024, 0, stream>>>(cnt_e, off_e, M_EDGES);
    exscan_kernel<<<1, 1024, 0, stream>>>(cnt_n, off_n, N_NODES);
    fill_kernel<<<nnz_blocks, 256, 0, stream>>>(node_idx, edge_idx, off_e, off_n,
                                                cur_e, cur_n, idx_e, idx_n);
    dinv_kernel<<<(N_NODES + 255) / 256, 256, 0, stream>>>(off_n, idx_n, cnt_e, dinv);
    wprep<<<(FT_DIM * HID + 255) / 256, 256, 0, stream>>>(W1[0], Wp[0][0], Wp[0][1], FT_DIM);
    wprep<<<(HID * HID + 255) / 256, 256, 0, stream>>>(W2[0], Wp[1][0], Wp[1][1], HID);
    wprep<<<(HID * HID + 255) / 256, 256, 0, stream>>>(W1[1], Wp[2][0], Wp[2][1], HID);
    wprep<<<(HID * HID + 255) / 256, 256, 0, stream>>>(W2[1], Wp[3][0], Wp[3][1], HID);
    fsplit<<<(N_NODES * FT_DIM / 4 + 255) / 256, 256, 0, stream>>>((const float4*)X,
                                                                   (u4v*)Xb, N_NODES * FT_DIM / 4);

    // ---------------- layer 0 ----------------
    gather_pool<2, false><<<M_EDGES / 4, 256, 0, stream>>>(off_e, idx_e, Xb, Eb, nullptr);
    gather_pool<2, true><<<N_NODES / 4, 256, 0, stream>>>(off_n, idx_n, Eb, Ph, Pl);
    gemm_pc<<<ggrid, 256, 0, stream>>>(Ph, Pl, Wp[0][0], Wp[0][1], b1[0], T,
                                       statsall + 0 * 512, FT_DIM);
    bn_finalize<<<1, 256, 0, stream>>>(statsall + 0 * 512, g1[0], be1[0], rows_inv,
                                       bnA + 0 * HID, bnC + 0 * HID);
    bn_split<true><<<(n4 + 255) / 256, 256, 0, stream>>>((const float4*)T, bnA + 0 * HID,
                                                         bnC + 0 * HID, (u4v*)Ahp, (u4v*)Alp, n4);
    gemm_pc<<<ggrid, 256, 0, stream>>>(Ahp, Alp, Wp[1][0], Wp[1][1], b2[0], T,
                                       statsall + 1 * 512, HID);
    bn_finalize<<<1, 256, 0, stream>>>(statsall + 1 * 512, bng[0], bnb[0], rows_inv,
                                       bnA + 1 * HID, bnC + 1 * HID);
    bn_split<false><<<(n4 + 255) / 256, 256, 0, stream>>>((const float4*)T, bnA + 1 * HID,
                                                          bnC + 1 * HID, (u4v*)Hb, nullptr, n4);
    // shared edge pass (layer-0 readout AND layer-1 pooling)
    gather_pool<4, false><<<M_EDGES / 4, 256, 0, stream>>>(off_e, idx_e, Hb, Eb, nullptr);
    gather_head<true><<<N_NODES / 4, 256, 0, stream>>>(off_n, idx_n, Eb, dinv, headW, headb,
                                                       onodes, Ph, Pl);

    // ---------------- layer 1 ----------------
    gemm_pc<<<ggrid, 256, 0, stream>>>(Ph, Pl, Wp[2][0], Wp[2][1], b1[1], T,
                                       statsall + 2 * 512, HID);
    bn_finalize<<<1, 256, 0, stream>>>(statsall + 2 * 512, g1[1], be1[1], rows_inv,
                                       bnA + 2 * HID, bnC + 2 * HID);
    bn_split<true><<<(n4 + 255) / 256, 256, 0, stream>>>((const float4*)T, bnA + 2 * HID,
                                                         bnC + 2 * HID, (u4v*)Ahp, (u4v*)Alp, n4);
    gemm_pc<<<ggrid, 256, 0, stream>>>(Ahp, Alp, Wp[3][0], Wp[3][1], b2[1], T,
                                       statsall + 3 * 512, HID);
    bn_finalize<<<1, 256, 0, stream>>>(statsall + 3 * 512, bng[1], bnb[1], rows_inv,
                                       bnA + 3 * HID, bnC + 3 * HID);
    bn_split<false><<<(n4 + 255) / 256, 256, 0, stream>>>((const float4*)T, bnA + 3 * HID,
                                                          bnC + 3 * HID, (u4v*)Hb, nullptr, n4);
    gather_pool<4, false><<<M_EDGES / 4, 256, 0, stream>>>(off_e, idx_e, Hb, Eb, nullptr);
    gather_head<false><<<N_NODES / 4, 256, 0, stream>>>(off_n, idx_n, Eb, dinv,
                                                        headW + (size_t)HID * NCLS, headb,
                                                        onodes, nullptr, nullptr);

    // ---------------- readout ----------------
    readout_accum<<<(N_NODES + 255) / 256, 256, 0, stream>>>(onodes, all_batch, racc, rcnt);
    readout_final<<<(NG * NCLS + 255) / 256, 256, 0, stream>>>(racc, rcnt, out);
}